// Round 6
// baseline (122.078 us; speedup 1.0000x reference)
//
#include <hip/hip_runtime.h>

// VectorQuantizer: x [2,8,48,48,48] f32, embed [512,8] f32
// d_out: loss (1) | out (1769472) | encodings (221184*512 = 113246208)
// R6: fused zero-stream + argmin loop (R5) with:
//  - 2 pts/thread, 1728 one-wave blocks (~1.7 waves/SIMD of TLP)
//  - ping-pong register prefetch of codebook pairs (LDS latency hidden)
//  - one float4 zero-store per lane per iteration

#pragma clang fp contract(off)

#define KCB   512
#define SPB   110592          // 48^3
#define NBLK  1728            // 221184 / 128 rows per block
#define OUT_OFF 1
#define ENC_OFF 1769473LL     // 1 + 2*8*SPB ; %4 == 1
#define G4_BASE 442369LL      // (ENC_OFF + 3) / 4

__global__ __launch_bounds__(64) void vq_main(const float* __restrict__ x,
                                              const float* __restrict__ e,
                                              float* __restrict__ dout,
                                              float* __restrict__ partials) {
    __shared__ float cb[KCB * 8];    // 16 KB codebook [512][8]
    __shared__ float sse[KCB];       // 2 KB row norms
    const int L   = threadIdx.x;     // 0..63, one wave per block
    const int blk = blockIdx.x;
    const int b   = (blk >= 864) ? 1 : 0;          // blocks don't straddle batch
    const int s0  = blk * 128 - b * SPB;           // row q*64+L -> spatial s0+q*64+L

    // x loads early: xv[q][c], coalesced 256B per (c,q)
    const float* xb = x + (size_t)b * (8 * SPB) + s0 + L;
    float xv[2][8];
    #pragma unroll
    for (int q = 0; q < 2; ++q)
        #pragma unroll
        for (int c = 0; c < 8; ++c)
            xv[q][c] = xb[(size_t)c * SPB + q * 64];

    // stage codebook (1024 float4, 16 per lane)
    {
        float4* cb4 = (float4*)cb;
        const float4* e4 = (const float4*)e;
        #pragma unroll
        for (int i = 0; i < 16; ++i) cb4[i * 64 + L] = e4[i * 64 + L];
    }
    __syncthreads();
    // row norms: numpy 8-elem pairwise tree (contract off: squares round first)
    #pragma unroll
    for (int j = 0; j < 8; ++j) {
        int r = j * 64 + L;
        const float* row = cb + (r << 3);
        sse[r] = ((row[0]*row[0] + row[1]*row[1]) + (row[2]*row[2] + row[3]*row[3]))
               + ((row[4]*row[4] + row[5]*row[5]) + (row[6]*row[6] + row[7]*row[7]));
    }
    __syncthreads();

    // sum(x^2), numpy tree, per point
    float sx[2];
    #pragma unroll
    for (int q = 0; q < 2; ++q)
        sx[q] = ((xv[q][0]*xv[q][0] + xv[q][1]*xv[q][1]) + (xv[q][2]*xv[q][2] + xv[q][3]*xv[q][3]))
              + ((xv[q][4]*xv[q][4] + xv[q][5]*xv[q][5]) + (xv[q][6]*xv[q][6] + xv[q][7]*xv[q][7]));

    float bestE[2] = {3.402823466e38f, 3.402823466e38f};
    float bestO[2] = {3.402823466e38f, 3.402823466e38f};
    int   idxE[2] = {0, 0}, idxO[2] = {1, 1};

    // block's enc region: 65536 floats at ENC_OFF + blk*65536 (%4==1):
    // 3 head floats, 16383 float4 slots, 1 tail float.
    float4* encb = (float4*)dout + (G4_BASE + (long long)blk * 16384);
    float*  encf = dout + (ENC_OFF + (long long)blk * 65536);
    const float4 z4 = make_float4(0.f, 0.f, 0.f, 0.f);

    // per-pair compute: rows k,k+1 against both points, bit-identical numerics
    auto pairstep = [&](const float4& r0a, const float4& r0b,
                        const float4& r1a, const float4& r1b,
                        const float2& s01, int k) {
        #pragma unroll
        for (int q = 0; q < 2; ++q) {
            float d0 =       xv[q][0] * r0a.x;
            d0 = __builtin_fmaf(xv[q][1], r0a.y, d0);
            d0 = __builtin_fmaf(xv[q][2], r0a.z, d0);
            d0 = __builtin_fmaf(xv[q][3], r0a.w, d0);
            d0 = __builtin_fmaf(xv[q][4], r0b.x, d0);
            d0 = __builtin_fmaf(xv[q][5], r0b.y, d0);
            d0 = __builtin_fmaf(xv[q][6], r0b.z, d0);
            d0 = __builtin_fmaf(xv[q][7], r0b.w, d0);
            float dist0 = __builtin_fmaf(-2.0f, d0, sx[q] + s01.x);

            float d1 =       xv[q][0] * r1a.x;
            d1 = __builtin_fmaf(xv[q][1], r1a.y, d1);
            d1 = __builtin_fmaf(xv[q][2], r1a.z, d1);
            d1 = __builtin_fmaf(xv[q][3], r1a.w, d1);
            d1 = __builtin_fmaf(xv[q][4], r1b.x, d1);
            d1 = __builtin_fmaf(xv[q][5], r1b.y, d1);
            d1 = __builtin_fmaf(xv[q][6], r1b.z, d1);
            d1 = __builtin_fmaf(xv[q][7], r1b.w, d1);
            float dist1 = __builtin_fmaf(-2.0f, d1, sx[q] + s01.y);

            bool l0 = dist0 < bestE[q];
            bestE[q] = l0 ? dist0 : bestE[q];
            idxE[q]  = l0 ? k     : idxE[q];
            bool l1 = dist1 < bestO[q];
            bestO[q] = l1 ? dist1 : bestO[q];
            idxO[q]  = l1 ? k + 1 : idxO[q];
        }
    };

    // ping-pong prefetch: pair p occupies cb[p*16 .. p*16+15]
    float4 a0, a1, a2, a3, b0, b1, b2, b3;
    float2 as, bs;
    {   const float4* p = (const float4*)cb;
        a0 = p[0]; a1 = p[1]; a2 = p[2]; a3 = p[3];
        as = *(const float2*)sse; }

    #pragma unroll 1
    for (int i = 0; i < 256; i += 2) {
        {   const float4* p = (const float4*)(cb + ((i + 1) << 4));
            b0 = p[0]; b1 = p[1]; b2 = p[2]; b3 = p[3];
            bs = *(const float2*)(sse + 2 * (i + 1)); }
        encb[(size_t)i * 64 + L] = z4;                 // slot i*64+L < 16383 always
        pairstep(a0, a1, a2, a3, as, 2 * i);

        {   int ip = (i + 2) & 255;                    // wraps harmlessly at end
            const float4* p = (const float4*)(cb + (ip << 4));
            a0 = p[0]; a1 = p[1]; a2 = p[2]; a3 = p[3];
            as = *(const float2*)(sse + 2 * ip); }
        if (i + 1 < 255 || L < 63)                     // slot (255,63) = next block's head
            encb[(size_t)(i + 1) * 64 + L] = z4;
        pairstep(b0, b1, b2, b3, bs, 2 * (i + 1));
    }

    // head / tail zeros of this block's region
    if (L < 3)   encf[L]     = 0.f;
    if (L == 63) encf[65535] = 0.f;

    // merge chains (global first-min tie rule)
    int bidx[2];
    #pragma unroll
    for (int q = 0; q < 2; ++q) {
        bool ow = (bestO[q] < bestE[q]) || ((bestO[q] == bestE[q]) && (idxO[q] < idxE[q]));
        bidx[q] = ow ? idxO[q] : idxE[q];
    }

    // all zero-stores of THIS wave complete, then scatter the ones
    asm volatile("s_waitcnt vmcnt(0)" ::: "memory");
    #pragma unroll
    for (int q = 0; q < 2; ++q)
        encf[(size_t)(q * 64 + L) * 512 + bidx[q]] = 1.0f;

    // out region + loss partial
    float part = 0.0f;
    float* outp = dout + OUT_OFF + (size_t)b * (8 * SPB) + s0 + L;
    #pragma unroll
    for (int q = 0; q < 2; ++q) {
        const float4* qr4 = (const float4*)(cb + (bidx[q] << 3));
        float4 qa = qr4[0], qb = qr4[1];
        float qv[8] = {qa.x, qa.y, qa.z, qa.w, qb.x, qb.y, qb.z, qb.w};
        #pragma unroll
        for (int c = 0; c < 8; ++c) {
            float dq = qv[c] - xv[q][c];
            part += dq * dq;
            outp[(size_t)c * SPB + q * 64] = qv[c];
        }
    }

    // deterministic wave tree reduction
    #pragma unroll
    for (int off = 32; off > 0; off >>= 1)
        part += __shfl_down(part, off, 64);
    if (L == 0) partials[blk] = part;
}

__global__ __launch_bounds__(256) void loss_kernel(const float* __restrict__ partials,
                                                   float* __restrict__ dout) {
    __shared__ float sred[256];
    int t = threadIdx.x;
    float a = 0.0f;
    for (int j = t; j < NBLK; j += 256) a += partials[j];  // fixed order
    sred[t] = a;
    __syncthreads();
    for (int off = 128; off > 0; off >>= 1) {
        if (t < off) sred[t] += sred[t + off];
        __syncthreads();
    }
    if (t == 0) {
        float m = sred[0] / 1769472.0f;
        m = fminf(fmaxf(m, 0.0f), 10.0f);
        dout[0] = m + 0.25f * m;   // q_latent + beta*e_latent (equal values)
    }
}

extern "C" void kernel_launch(void* const* d_in, const int* in_sizes, int n_in,
                              void* d_out, int out_size, void* d_ws, size_t ws_size,
                              hipStream_t stream) {
    const float* x = (const float*)d_in[0];
    const float* e = (const float*)d_in[1];
    float* dout     = (float*)d_out;
    float* partials = (float*)d_ws;     // 1728 floats

    hipLaunchKernelGGL(vq_main,     dim3(NBLK), dim3(64),  0, stream, x, e, dout, partials);
    hipLaunchKernelGGL(loss_kernel, dim3(1),    dim3(256), 0, stream, partials, dout);
}